// Round 1
// baseline (727.672 us; speedup 1.0000x reference)
//
#include <hip/hip_runtime.h>
#include <hip/hip_bf16.h>

// HardMemory: x[32,512,64,64] f32, memory[1024,512] f32.
// sim = cos(x_pixel, mem_row); out[b,c,n] = memory[argmax][c] * (max>0.8)
// Pipeline: (1) normalize memory -> bf16, (2) MFMA GEMM + fused max/argmax,
// (3) masked gather via LDS row-transpose (coalesced both sides).

typedef __attribute__((ext_vector_type(8))) short short8;   // 8 bf16 (4 VGPRs)
typedef __attribute__((ext_vector_type(4))) float f32x4;

#define THRESH 0.8f
#define EPSN   1e-12f

__device__ __forceinline__ short f2bf(float f) {
    union { float f; unsigned u; } v; v.f = f;
    unsigned r = v.u + 0x7fffu + ((v.u >> 16) & 1u);   // RNE
    return (short)(r >> 16);
}

// ---------------- kernel 1: normalize memory rows -> bf16 ----------------
__global__ __launch_bounds__(256) void norm_mem_kernel(
        const float* __restrict__ mem, short* __restrict__ mem_bf) {
    const int row = blockIdx.x;          // 1024
    const int t   = threadIdx.x;         // 256
    const float* r = mem + (size_t)row * 512;
    float v0 = r[t], v1 = r[t + 256];
    float ss = v0 * v0 + v1 * v1;
    #pragma unroll
    for (int off = 32; off; off >>= 1) ss += __shfl_down(ss, off, 64);
    __shared__ float part[4];
    __shared__ float rinv_s;
    if ((t & 63) == 0) part[t >> 6] = ss;
    __syncthreads();
    if (t == 0) {
        float s = part[0] + part[1] + part[2] + part[3];
        rinv_s = 1.0f / fmaxf(sqrtf(s), EPSN);
    }
    __syncthreads();
    float rinv = rinv_s;
    mem_bf[(size_t)row * 512 + t]       = f2bf(v0 * rinv);
    mem_bf[(size_t)row * 512 + t + 256] = f2bf(v1 * rinv);
}

// ---------------- kernel 2: GEMM + fused row max/argmax ----------------
// Block: 64 pixels x all 1024 mems. 256 threads = 4 waves.
// Wave tile: 64 pixels x 64 mems -> 16 mfma_f32_16x16x32_bf16 per K-step of 32
// (acc[4][4]), fed by 4 LDS A-reads + 4 global B-reads, BOTH with 1-step
// register prefetch (A prefetch is new: the lgkmcnt wait now lands after the
// MFMA burst instead of in front of it). mc loop 8 -> 4: same B traffic,
// half the A-reads/loop overhead, 2x longer MFMA bursts to hide L2 latency
// at the LDS-pinned 2-waves/SIMD occupancy.
// kk loop is FORCIBLY ROLLED (#pragma unroll 1): full unroll let the
// scheduler hoist loads -> VGPR live-range explosion -> scratch spill
// (rounds 2-4 of prior session). Rolled body ~175 regs, no spill.
__global__ __launch_bounds__(256, 2) void simmax_kernel(
        const float* __restrict__ x, const short* __restrict__ memn,
        int* __restrict__ selv) {
    __shared__ short xs[64 * 512];       // 64 KiB, A-tile pre-fragmented
    __shared__ float part[4][64];        // per-wave partial ||x||^2
    __shared__ float redv[4][64];        // per-wave max
    __shared__ int   redi[4][64];        // per-wave argmax

    const int t  = threadIdx.x;          // 0..255
    const int b  = blockIdx.y;           // 32
    const int n0 = blockIdx.x * 64;      // 64 pixel tiles
    const int p  = t & 63;
    const int w  = t >> 6;               // wave 0..3

    // ---- stage X tile: x[b, c, n0+p] -> xs[(c/8)*64 + p][c%8] as bf16 ----
    const float* xb = x + ((size_t)b * 512) * 4096 + n0 + p;
    float ss = 0.f;
    for (int oct = w; oct < 64; oct += 4) {
        short8 pk;
        #pragma unroll
        for (int i = 0; i < 8; ++i) {
            float v = xb[(size_t)(oct * 8 + i) * 4096];
            ss += v * v;
            pk[i] = f2bf(v);
        }
        *(short8*)&xs[(oct * 64 + p) * 8] = pk;
    }
    part[w][p] = ss;
    __syncthreads();

    float xnorm_reg = 1.0f;
    if (t < 64) {
        float s = part[0][t] + part[1][t] + part[2][t] + part[3][t];
        xnorm_reg = fmaxf(sqrtf(s), EPSN);
    }

    const int lane = t & 63;
    const int quad = lane >> 4;
    const int l15  = lane & 15;

    float runv[4][4];
    int   runi[4][4];
    #pragma unroll
    for (int i = 0; i < 4; ++i)
        #pragma unroll
        for (int r = 0; r < 4; ++r) { runv[i][r] = -1e30f; runi[i][r] = 0; }

    #pragma unroll 1
    for (int mc = 0; mc < 4; ++mc) {
        f32x4 acc[4][4];
        #pragma unroll
        for (int i = 0; i < 4; ++i)
            #pragma unroll
            for (int j = 0; j < 4; ++j) acc[i][j] = (f32x4){0.f, 0.f, 0.f, 0.f};

        const int mb = mc * 256 + w * 64;          // this wave's 64 mems
        const short* bptr = memn + (size_t)(mb + l15) * 512 + quad * 8;

        short8 bcur[4];
        #pragma unroll
        for (int j = 0; j < 4; ++j)
            bcur[j] = *(const short8*)(bptr + j * 8192);   // rows 16 apart
        short8 acur[4];
        #pragma unroll
        for (int i = 0; i < 4; ++i)
            acur[i] = *(const short8*)&xs[(quad * 64 + i * 16 + l15) * 8];

        // NOTE: last B prefetch reads <=64 B past mem_bf into the selv region
        // of d_ws (in-bounds of the allocation, values unused; benign read of
        // concurrently-written selv bytes). Last A prefetch wraps via &511
        // (re-reads oct=quad, values unused).
        #pragma unroll 1
        for (int kk = 0; kk < 512; kk += 32) {
            short8 bnxt[4];
            #pragma unroll
            for (int j = 0; j < 4; ++j)
                bnxt[j] = *(const short8*)(bptr + j * 8192 + kk + 32);
            const int octn = (((kk + 32) & 511) >> 3) + quad;
            short8 anxt[4];
            #pragma unroll
            for (int i = 0; i < 4; ++i)
                anxt[i] = *(const short8*)&xs[(octn * 64 + i * 16 + l15) * 8];
            #pragma unroll
            for (int i = 0; i < 4; ++i)
                #pragma unroll
                for (int j = 0; j < 4; ++j)
                    acc[i][j] = __builtin_amdgcn_mfma_f32_16x16x32_bf16(
                        acur[i], bcur[j], acc[i][j], 0, 0, 0);
            #pragma unroll
            for (int j = 0; j < 4; ++j) bcur[j] = bnxt[j];
            #pragma unroll
            for (int i = 0; i < 4; ++i) acur[i] = anxt[i];
        }

        #pragma unroll
        for (int i = 0; i < 4; ++i)
            #pragma unroll
            for (int j = 0; j < 4; ++j) {        // ascending col within wave
                const int cb = mb + j * 16 + l15;
                #pragma unroll
                for (int r = 0; r < 4; ++r) {
                    float v = acc[i][j][r];
                    if (v > runv[i][r]) { runv[i][r] = v; runi[i][r] = cb; }
                }
            }
    }

    // ---- cross-lane max/argmax (cols live on 16 lanes of each quad) ----
    #pragma unroll
    for (int i = 0; i < 4; ++i)
        #pragma unroll
        for (int r = 0; r < 4; ++r) {
            float v = runv[i][r]; int ix = runi[i][r];
            #pragma unroll
            for (int off = 1; off < 16; off <<= 1) {
                float ov = __shfl_xor(v, off, 64);
                int   oi = __shfl_xor(ix, off, 64);
                if (ov > v || (ov == v && oi < ix)) { v = ov; ix = oi; }
            }
            if (l15 == 0) {
                const int pl = i * 16 + quad * 4 + r;   // pixel row 0..63
                redv[w][pl] = v;
                redi[w][pl] = ix;
            }
        }

    __syncthreads();
    if (t < 64) {
        float v = redv[0][t]; int ix = redi[0][t];
        #pragma unroll
        for (int c = 1; c < 4; ++c) {            // index-based tie-break
            float ov = redv[c][t]; int oi = redi[c][t];
            if (ov > v || (ov == v && oi < ix)) { v = ov; ix = oi; }
        }
        float maxval = v / xnorm_reg;
        selv[(size_t)b * 4096 + n0 + t] = (maxval > THRESH) ? ix : -1;
    }
}

// ---------------- kernel 3: masked gather via LDS transpose ----------------
// Old version did per-lane 4 B gathers mem[sel*512+c]: every lane a distinct
// 128 B line -> address-path serialization dominated (~300 us). Now: block
// owns 32 pixels; gather the 32 selected rows COALESCED (full-wave f32x4 row
// reads, rows L2-resident) into ls[32][516], then write out[b,c,n0+p] as
// aligned f32x4 along n (128 B contiguous per channel). LDS read side has a
// benign 4-way conflict; kernel is HBM-write-bound.
__global__ __launch_bounds__(256) void scatter_kernel(
        const float* __restrict__ mem, const int* __restrict__ selv,
        float* __restrict__ out) {
    __shared__ float ls[32][516];        // stride 516: f32x4-aligned rows
    __shared__ int   sel_s[32];
    const int t    = threadIdx.x;        // 256
    const int w    = t >> 6;             // wave 0..3
    const int lane = t & 63;
    const int n0   = blockIdx.x * 32;    // 128 pixel tiles
    const int b    = blockIdx.y;         // 32

    if (t < 32) sel_s[t] = selv[(size_t)b * 4096 + n0 + t];
    __syncthreads();

    // gather: wave w owns rows p = w*8 .. w*8+7; 2 full-wave f32x4 passes/row
    #pragma unroll
    for (int pr = 0; pr < 8; ++pr) {
        const int p = w * 8 + pr;
        const int s = sel_s[p];
        if (s < 0) {
            *(f32x4*)&ls[p][lane * 4]       = (f32x4){0.f, 0.f, 0.f, 0.f};
            *(f32x4*)&ls[p][lane * 4 + 256] = (f32x4){0.f, 0.f, 0.f, 0.f};
        } else {
            const float* r = mem + (size_t)s * 512;
            *(f32x4*)&ls[p][lane * 4]       = *(const f32x4*)&r[lane * 4];
            *(f32x4*)&ls[p][lane * 4 + 256] = *(const f32x4*)&r[lane * 4 + 256];
        }
    }
    __syncthreads();

    // write: wave w owns c = w*128..w*128+127; per pass 8 c x 32 n (f32x4)
    const int cl = lane >> 3;            // 0..7: channel within pass
    const int p4 = (lane & 7) * 4;       // 0,4,..28: pixel quad
    float* ob = out + (size_t)b * 512 * 4096 + n0;
    #pragma unroll
    for (int cp = 0; cp < 16; ++cp) {
        const int c = w * 128 + cp * 8 + cl;
        f32x4 v;
        v.x = ls[p4 + 0][c];
        v.y = ls[p4 + 1][c];
        v.z = ls[p4 + 2][c];
        v.w = ls[p4 + 3][c];
        __builtin_nontemporal_store(v, (f32x4*)&ob[(size_t)c * 4096 + p4]);
    }
}

extern "C" void kernel_launch(void* const* d_in, const int* in_sizes, int n_in,
                              void* d_out, int out_size, void* d_ws, size_t ws_size,
                              hipStream_t stream) {
    const float* x   = (const float*)d_in[0];   // [32,512,64,64]
    const float* mem = (const float*)d_in[1];   // [1024,512]
    short* mem_bf = (short*)d_ws;                       // 1 MiB bf16 normalized
    int*   selv   = (int*)((char*)d_ws + (1 << 20));    // 512 KiB selections
    float* out    = (float*)d_out;

    norm_mem_kernel<<<dim3(1024), dim3(256), 0, stream>>>(mem, mem_bf);
    simmax_kernel<<<dim3(64, 32), dim3(256), 0, stream>>>(x, mem_bf, selv);
    scatter_kernel<<<dim3(128, 32), dim3(256), 0, stream>>>(mem, selv, out);
}

// Round 2
// 692.913 us; speedup vs baseline: 1.0502x; 1.0502x over previous
//
#include <hip/hip_runtime.h>
#include <hip/hip_bf16.h>

// HardMemory: x[32,512,64,64] f32, memory[1024,512] f32.
// sim = cos(x_pixel, mem_row); out[b,c,n] = memory[argmax][c] * (max>0.8)
// Pipeline: (1) normalize memory -> bf16, (2) MFMA GEMM + fused max/argmax,
// (3) masked gather via LDS row-transpose (coalesced both sides).

typedef __attribute__((ext_vector_type(8))) short short8;   // 8 bf16 (4 VGPRs)
typedef __attribute__((ext_vector_type(4))) float f32x4;

#define THRESH 0.8f
#define EPSN   1e-12f

__device__ __forceinline__ short f2bf(float f) {
    union { float f; unsigned u; } v; v.f = f;
    unsigned r = v.u + 0x7fffu + ((v.u >> 16) & 1u);   // RNE
    return (short)(r >> 16);
}

// ---------------- kernel 1: normalize memory rows -> bf16 ----------------
__global__ __launch_bounds__(256) void norm_mem_kernel(
        const float* __restrict__ mem, short* __restrict__ mem_bf) {
    const int row = blockIdx.x;          // 1024
    const int t   = threadIdx.x;         // 256
    const float* r = mem + (size_t)row * 512;
    float v0 = r[t], v1 = r[t + 256];
    float ss = v0 * v0 + v1 * v1;
    #pragma unroll
    for (int off = 32; off; off >>= 1) ss += __shfl_down(ss, off, 64);
    __shared__ float part[4];
    __shared__ float rinv_s;
    if ((t & 63) == 0) part[t >> 6] = ss;
    __syncthreads();
    if (t == 0) {
        float s = part[0] + part[1] + part[2] + part[3];
        rinv_s = 1.0f / fmaxf(sqrtf(s), EPSN);
    }
    __syncthreads();
    float rinv = rinv_s;
    mem_bf[(size_t)row * 512 + t]       = f2bf(v0 * rinv);
    mem_bf[(size_t)row * 512 + t + 256] = f2bf(v1 * rinv);
}

// ---------------- kernel 2: GEMM + fused row max/argmax ----------------
// Block: 64 pixels x all 1024 mems. 512 threads = 8 waves sharing ONE 64 KiB
// A-tile (round-1 lesson: 4-wave block was LDS-pinned at 2 blocks/CU = 2
// waves/SIMD -> latency-bound at MfmaUtil 14%. Same LDS with 8 waves/block
// -> 16 waves/CU = 4 waves/SIMD: TLP, not ILP, is the latency cover).
// Wave tile: 64 pixels x 32 mems -> 8 mfma_f32_16x16x32_bf16 per K-step of 32
// (acc[4][2]), 4 LDS A-reads direct (no reg-prefetch: round-1 showed it only
// added pressure), 2 global B-reads with 1-step register prefetch.
// kk loop FORCIBLY ROLLED (#pragma unroll 1): full unroll -> load hoisting ->
// VGPR explosion -> scratch spill (rounds 2-4 of prior session).
// __launch_bounds__(512,4) caps at 128 VGPR (est ~120) to hold 4 waves/SIMD.
__global__ __launch_bounds__(512, 4) void simmax_kernel(
        const float* __restrict__ x, const short* __restrict__ memn,
        int* __restrict__ selv) {
    __shared__ short xs[64 * 512];       // 64 KiB, A-tile pre-fragmented
    __shared__ float part[8][64];        // per-wave partial ||x||^2
    __shared__ float redv[8][64];        // per-wave max
    __shared__ int   redi[8][64];        // per-wave argmax

    const int t  = threadIdx.x;          // 0..511
    const int b  = blockIdx.y;           // 32
    const int n0 = blockIdx.x * 64;      // 64 pixel tiles
    const int p  = t & 63;
    const int w  = t >> 6;               // wave 0..7

    // ---- stage X tile: x[b, c, n0+p] -> xs[(c/8)*64 + p][c%8] as bf16 ----
    const float* xb = x + ((size_t)b * 512) * 4096 + n0 + p;
    float ss = 0.f;
    for (int oct = w; oct < 64; oct += 8) {
        short8 pk;
        #pragma unroll
        for (int i = 0; i < 8; ++i) {
            float v = xb[(size_t)(oct * 8 + i) * 4096];
            ss += v * v;
            pk[i] = f2bf(v);
        }
        *(short8*)&xs[(oct * 64 + p) * 8] = pk;
    }
    part[w][p] = ss;
    __syncthreads();

    float xnorm_reg = 1.0f;
    if (t < 64) {
        float s = part[0][t];
        #pragma unroll
        for (int ww = 1; ww < 8; ++ww) s += part[ww][t];
        xnorm_reg = fmaxf(sqrtf(s), EPSN);
    }

    const int lane = t & 63;
    const int quad = lane >> 4;
    const int l15  = lane & 15;

    float runv[4][4];
    int   runi[4][4];
    #pragma unroll
    for (int i = 0; i < 4; ++i)
        #pragma unroll
        for (int r = 0; r < 4; ++r) { runv[i][r] = -1e30f; runi[i][r] = 0; }

    #pragma unroll 1
    for (int mc = 0; mc < 4; ++mc) {
        f32x4 acc[4][2];
        #pragma unroll
        for (int i = 0; i < 4; ++i)
            #pragma unroll
            for (int j = 0; j < 2; ++j) acc[i][j] = (f32x4){0.f, 0.f, 0.f, 0.f};

        const int mb = mc * 256 + w * 32;          // this wave's 32 mems
        const short* bptr = memn + (size_t)(mb + l15) * 512 + quad * 8;

        short8 bcur[2];
        #pragma unroll
        for (int j = 0; j < 2; ++j)
            bcur[j] = *(const short8*)(bptr + j * 8192);   // rows 16 apart

        // NOTE: last B prefetch reads <=16.5 KiB past mem_bf into the selv
        // region of d_ws (in-bounds of the allocation, values unused).
        #pragma unroll 1
        for (int kk = 0; kk < 512; kk += 32) {
            short8 bnxt[2];
            #pragma unroll
            for (int j = 0; j < 2; ++j)
                bnxt[j] = *(const short8*)(bptr + j * 8192 + kk + 32);
            const int oct = (kk >> 3) + quad;
            short8 a[4];
            #pragma unroll
            for (int i = 0; i < 4; ++i)
                a[i] = *(const short8*)&xs[(oct * 64 + i * 16 + l15) * 8];
            #pragma unroll
            for (int i = 0; i < 4; ++i)
                #pragma unroll
                for (int j = 0; j < 2; ++j)
                    acc[i][j] = __builtin_amdgcn_mfma_f32_16x16x32_bf16(
                        a[i], bcur[j], acc[i][j], 0, 0, 0);
            #pragma unroll
            for (int j = 0; j < 2; ++j) bcur[j] = bnxt[j];
        }

        #pragma unroll
        for (int i = 0; i < 4; ++i)
            #pragma unroll
            for (int j = 0; j < 2; ++j) {        // ascending col within wave
                const int cb = mb + j * 16 + l15;
                #pragma unroll
                for (int r = 0; r < 4; ++r) {
                    float v = acc[i][j][r];
                    if (v > runv[i][r]) { runv[i][r] = v; runi[i][r] = cb; }
                }
            }
    }

    // ---- cross-lane max/argmax (cols live on 16 lanes of each quad) ----
    #pragma unroll
    for (int i = 0; i < 4; ++i)
        #pragma unroll
        for (int r = 0; r < 4; ++r) {
            float v = runv[i][r]; int ix = runi[i][r];
            #pragma unroll
            for (int off = 1; off < 16; off <<= 1) {
                float ov = __shfl_xor(v, off, 64);
                int   oi = __shfl_xor(ix, off, 64);
                if (ov > v || (ov == v && oi < ix)) { v = ov; ix = oi; }
            }
            if (l15 == 0) {
                const int pl = i * 16 + quad * 4 + r;   // pixel row 0..63
                redv[w][pl] = v;
                redi[w][pl] = ix;
            }
        }

    __syncthreads();
    if (t < 64) {
        float v = redv[0][t]; int ix = redi[0][t];
        #pragma unroll
        for (int c = 1; c < 8; ++c) {            // index-based tie-break
            float ov = redv[c][t]; int oi = redi[c][t];
            if (ov > v || (ov == v && oi < ix)) { v = ov; ix = oi; }
        }
        float maxval = v / xnorm_reg;
        selv[(size_t)b * 4096 + n0 + t] = (maxval > THRESH) ? ix : -1;
    }
}

// ---------------- kernel 3: masked gather via LDS transpose ----------------
// Coalesced both sides: gather selected rows with full-wave f32x4 reads into
// ls[32][516], transpose-write out[b,c,n0..n0+32) as aligned f32x4 along n.
// A/B vs rounds 0-1: PLAIN stores replace __builtin_nontemporal_store. Both
// prior rounds (radically different gather patterns, same nt-store) left an
// identical ~315 us residual at ~0.85 TB/s write -> theory: nt-store takes an
// uncached, non-write-combining path. Plain stores drain through L2.
__global__ __launch_bounds__(256) void scatter_kernel(
        const float* __restrict__ mem, const int* __restrict__ selv,
        float* __restrict__ out) {
    __shared__ float ls[32][516];        // stride 516: f32x4-aligned rows
    __shared__ int   sel_s[32];
    const int t    = threadIdx.x;        // 256
    const int w    = t >> 6;             // wave 0..3
    const int lane = t & 63;
    const int n0   = blockIdx.x * 32;    // 128 pixel tiles
    const int b    = blockIdx.y;         // 32

    if (t < 32) sel_s[t] = selv[(size_t)b * 4096 + n0 + t];
    __syncthreads();

    // gather: wave w owns rows p = w*8 .. w*8+7; 2 full-wave f32x4 passes/row
    #pragma unroll
    for (int pr = 0; pr < 8; ++pr) {
        const int p = w * 8 + pr;
        const int s = sel_s[p];
        if (s < 0) {
            *(f32x4*)&ls[p][lane * 4]       = (f32x4){0.f, 0.f, 0.f, 0.f};
            *(f32x4*)&ls[p][lane * 4 + 256] = (f32x4){0.f, 0.f, 0.f, 0.f};
        } else {
            const float* r = mem + (size_t)s * 512;
            *(f32x4*)&ls[p][lane * 4]       = *(const f32x4*)&r[lane * 4];
            *(f32x4*)&ls[p][lane * 4 + 256] = *(const f32x4*)&r[lane * 4 + 256];
        }
    }
    __syncthreads();

    // write: wave w owns c = w*128..w*128+127; per pass 8 c x 32 n (f32x4)
    const int cl = lane >> 3;            // 0..7: channel within pass
    const int p4 = (lane & 7) * 4;       // 0,4,..28: pixel quad
    float* ob = out + (size_t)b * 512 * 4096 + n0;
    #pragma unroll
    for (int cp = 0; cp < 16; ++cp) {
        const int c = w * 128 + cp * 8 + cl;
        f32x4 v;
        v.x = ls[p4 + 0][c];
        v.y = ls[p4 + 1][c];
        v.z = ls[p4 + 2][c];
        v.w = ls[p4 + 3][c];
        *(f32x4*)&ob[(size_t)c * 4096 + p4] = v;
    }
}

extern "C" void kernel_launch(void* const* d_in, const int* in_sizes, int n_in,
                              void* d_out, int out_size, void* d_ws, size_t ws_size,
                              hipStream_t stream) {
    const float* x   = (const float*)d_in[0];   // [32,512,64,64]
    const float* mem = (const float*)d_in[1];   // [1024,512]
    short* mem_bf = (short*)d_ws;                       // 1 MiB bf16 normalized
    int*   selv   = (int*)((char*)d_ws + (1 << 20));    // 512 KiB selections
    float* out    = (float*)d_out;

    norm_mem_kernel<<<dim3(1024), dim3(256), 0, stream>>>(mem, mem_bf);
    simmax_kernel<<<dim3(64, 32), dim3(512), 0, stream>>>(x, mem_bf, selv);
    scatter_kernel<<<dim3(128, 32), dim3(256), 0, stream>>>(mem, selv, out);
}

// Round 3
// 565.309 us; speedup vs baseline: 1.2872x; 1.2257x over previous
//
#include <hip/hip_runtime.h>
#include <hip/hip_bf16.h>

// HardMemory: x[32,512,64,64] f32, memory[1024,512] f32.
// sim = cos(x_pixel, mem_row); out[b,c,n] = memory[argmax][c] * (max>0.8)
// Pipeline (2 kernels): (1) normalize memory -> bf16 in PRE-FRAGMENTED MFMA
// layout, (2) MFMA GEMM + fused max/argmax + fused gather/transpose output.
//
// Round-2 lessons baked in:
//  - Occupancy 23->46% bought only 9%: simmax is not TLP-starved. Theory: the
//    old B-loads (16 rows x 64B segments per instr = 16 L2 requests, half of
//    every line wasted) saturate the request queue; vmcnt drains every step.
//    Fix: memnF layout makes every wave B-load ONE contiguous 1 KiB.
//  - scatter rewrites (nt vs plain stores) left an identical ~315us residual
//    -> fuse the output production into simmax so it overlaps GEMM of other
//    blocks and its cost is visible in this kernel's counters.

typedef __attribute__((ext_vector_type(8))) short short8;   // 8 bf16 (4 VGPRs)
typedef __attribute__((ext_vector_type(4))) float f32x4;

#define THRESH 0.8f
#define EPSN   1e-12f

__device__ __forceinline__ short f2bf(float f) {
    union { float f; unsigned u; } v; v.f = f;
    unsigned r = v.u + 0x7fffu + ((v.u >> 16) & 1u);   // RNE
    return (short)(r >> 16);
}

// ---------------- kernel 1: normalize memory rows -> fragmented bf16 --------
// memnF layout: for mem-group g=m/16, K-step kks=k/32, quad=(k%32)/8, l15=m%16:
//   memnF[g*8192 + kks*512 + (quad*16+l15)*8 + (k%8)]
// so a wave's B-fragment load for (group, kks) is ONE contiguous 1 KiB:
//   lane (quad*16+l15) reads short8 at [g*8192 + kks*512 + lane*8].
__global__ __launch_bounds__(256) void norm_mem_kernel(
        const float* __restrict__ mem, short* __restrict__ memnF) {
    const int m = blockIdx.x;            // 1024
    const int t = threadIdx.x;           // 256
    const float* r = mem + (size_t)m * 512;
    const float2 v = *(const float2*)&r[2 * t];
    float ss = v.x * v.x + v.y * v.y;
    #pragma unroll
    for (int off = 32; off; off >>= 1) ss += __shfl_down(ss, off, 64);
    __shared__ float part[4];
    __shared__ float rinv_s;
    if ((t & 63) == 0) part[t >> 6] = ss;
    __syncthreads();
    if (t == 0) {
        float s = part[0] + part[1] + part[2] + part[3];
        rinv_s = 1.0f / fmaxf(sqrtf(s), EPSN);
    }
    __syncthreads();
    const float rinv = rinv_s;
    const unsigned u0 = (unsigned short)f2bf(v.x * rinv);
    const unsigned u1 = (unsigned short)f2bf(v.y * rinv);
    const int k0 = t * 2;
    const size_t off = (size_t)(m >> 4) * 8192 + (size_t)(k0 >> 5) * 512
                     + (size_t)((((k0 >> 3) & 3) * 16 + (m & 15)) * 8 + (k0 & 7));
    *(unsigned*)&memnF[off] = u0 | (u1 << 16);
}

// ---------------- kernel 2: GEMM + max/argmax + fused output ----------------
// Block: 64 pixels x all 1024 mems, 512 threads = 8 waves, one shared 64 KiB
// A-tile. Wave tile 64 px x 32 mems: 8 mfma_f32_16x16x32_bf16 per K-step,
// B register-prefetched one phase ahead (ping-pong, no v_mov copies),
// A read direct from LDS. kk loop rolled (#pragma unroll 1; full unroll ->
// VGPR explosion/spill, prior session). After argmax: gather selected memory
// rows and transpose-write the block's 128 KiB output via LDS (reuses A-tile
// space), two 32-pixel halves.
__global__ __launch_bounds__(512, 4) void simmax_kernel(
        const float* __restrict__ x, const short* __restrict__ memnF,
        const float* __restrict__ mem, float* __restrict__ out) {
    __shared__ __align__(16) char smem[66048];   // xs: 64 KiB | ls: 32x516 f32
    short* xs = (short*)smem;
    float (*ls)[516] = (float(*)[516])smem;
    __shared__ float part[8][64];        // per-wave partial ||x||^2
    __shared__ float redv[8][64];        // per-wave max
    __shared__ int   redi[8][64];        // per-wave argmax
    __shared__ int   selp[64];           // final selection per pixel

    const int t  = threadIdx.x;          // 0..511
    const int b  = blockIdx.y;           // 32
    const int n0 = blockIdx.x * 64;      // 64 pixel tiles
    const int p  = t & 63;
    const int w  = t >> 6;               // wave 0..7

    // ---- stage X tile: x[b, c, n0+p] -> xs[(c/8)*64 + p][c%8] as bf16 ----
    const float* xb = x + ((size_t)b * 512) * 4096 + n0 + p;
    float ss = 0.f;
    for (int oct = w; oct < 64; oct += 8) {
        short8 pk;
        #pragma unroll
        for (int i = 0; i < 8; ++i) {
            float v = xb[(size_t)(oct * 8 + i) * 4096];
            ss += v * v;
            pk[i] = f2bf(v);
        }
        *(short8*)&xs[(oct * 64 + p) * 8] = pk;
    }
    part[w][p] = ss;
    __syncthreads();

    float xnorm_reg = 1.0f;
    if (t < 64) {
        float s = part[0][t];
        #pragma unroll
        for (int ww = 1; ww < 8; ++ww) s += part[ww][t];
        xnorm_reg = fmaxf(sqrtf(s), EPSN);
    }

    const int lane = t & 63;
    const int quad = lane >> 4;
    const int l15  = lane & 15;

    float runv[4][4];
    int   runi[4][4];
    #pragma unroll
    for (int i = 0; i < 4; ++i)
        #pragma unroll
        for (int r = 0; r < 4; ++r) { runv[i][r] = -1e30f; runi[i][r] = 0; }

    #pragma unroll 1
    for (int mc = 0; mc < 4; ++mc) {
        f32x4 acc[4][2];
        #pragma unroll
        for (int i = 0; i < 4; ++i)
            #pragma unroll
            for (int j = 0; j < 2; ++j) acc[i][j] = (f32x4){0.f, 0.f, 0.f, 0.f};

        const int mb = mc * 256 + w * 32;          // this wave's 32 mems
        const int g0 = mb >> 4;                    // 16-mem fragment group
        const short* bb0 = memnF + (size_t)g0 * 8192 + lane * 8;
        const short* bb1 = bb0 + 8192;

        short8 bA[2], bB[2];
        bA[0] = *(const short8*)(bb0);             // contiguous 1 KiB / wave
        bA[1] = *(const short8*)(bb1);

        #pragma unroll 1
        for (int kks = 0; kks < 16; kks += 2) {
            // phase A: prefetch kks+1, compute kks
            bB[0] = *(const short8*)(bb0 + (kks + 1) * 512);
            bB[1] = *(const short8*)(bb1 + (kks + 1) * 512);
            {
                const int oct = kks * 4 + quad;
                short8 a[4];
                #pragma unroll
                for (int i = 0; i < 4; ++i)
                    a[i] = *(const short8*)&xs[(oct * 64 + i * 16 + l15) * 8];
                #pragma unroll
                for (int i = 0; i < 4; ++i)
                    #pragma unroll
                    for (int j = 0; j < 2; ++j)
                        acc[i][j] = __builtin_amdgcn_mfma_f32_16x16x32_bf16(
                            a[i], bA[j], acc[i][j], 0, 0, 0);
            }
            // phase B: prefetch kks+2 (wraps to 0 on last iter, in-bounds,
            // values unused), compute kks+1
            const int kn = (kks + 2) & 15;
            bA[0] = *(const short8*)(bb0 + kn * 512);
            bA[1] = *(const short8*)(bb1 + kn * 512);
            {
                const int oct = (kks + 1) * 4 + quad;
                short8 a[4];
                #pragma unroll
                for (int i = 0; i < 4; ++i)
                    a[i] = *(const short8*)&xs[(oct * 64 + i * 16 + l15) * 8];
                #pragma unroll
                for (int i = 0; i < 4; ++i)
                    #pragma unroll
                    for (int j = 0; j < 2; ++j)
                        acc[i][j] = __builtin_amdgcn_mfma_f32_16x16x32_bf16(
                            a[i], bB[j], acc[i][j], 0, 0, 0);
            }
        }

        #pragma unroll
        for (int i = 0; i < 4; ++i)
            #pragma unroll
            for (int j = 0; j < 2; ++j) {        // ascending col within wave
                const int cb = mb + j * 16 + l15;
                #pragma unroll
                for (int r = 0; r < 4; ++r) {
                    float v = acc[i][j][r];
                    if (v > runv[i][r]) { runv[i][r] = v; runi[i][r] = cb; }
                }
            }
    }

    // ---- cross-lane max/argmax (cols live on 16 lanes of each quad) ----
    #pragma unroll
    for (int i = 0; i < 4; ++i)
        #pragma unroll
        for (int r = 0; r < 4; ++r) {
            float v = runv[i][r]; int ix = runi[i][r];
            #pragma unroll
            for (int off = 1; off < 16; off <<= 1) {
                float ov = __shfl_xor(v, off, 64);
                int   oi = __shfl_xor(ix, off, 64);
                if (ov > v || (ov == v && oi < ix)) { v = ov; ix = oi; }
            }
            if (l15 == 0) {
                const int pl = i * 16 + quad * 4 + r;   // pixel row 0..63
                redv[w][pl] = v;
                redi[w][pl] = ix;
            }
        }

    __syncthreads();
    if (t < 64) {
        float v = redv[0][t]; int ix = redi[0][t];
        #pragma unroll
        for (int c = 1; c < 8; ++c) {            // index-based tie-break
            float ov = redv[c][t]; int oi = redi[c][t];
            if (ov > v || (ov == v && oi < ix)) { v = ov; ix = oi; }
        }
        float maxval = v / xnorm_reg;
        selp[t] = (maxval > THRESH) ? ix : -1;
    }
    __syncthreads();                      // selp ready; xs reads all done

    // ---- fused gather + transpose output: two halves of 32 pixels ----
    // gather: wave w owns 4 rows/half, full-wave f32x4 row reads (L2-hot).
    // write: wave w owns 64 channels; per instr 8 channels x 128 B contiguous.
    #pragma unroll 1
    for (int half = 0; half < 2; ++half) {
        #pragma unroll
        for (int pr = 0; pr < 4; ++pr) {
            const int pp = w * 4 + pr;
            const int s = selp[half * 32 + pp];
            if (s < 0) {
                *(f32x4*)&ls[pp][lane * 4]       = (f32x4){0.f, 0.f, 0.f, 0.f};
                *(f32x4*)&ls[pp][lane * 4 + 256] = (f32x4){0.f, 0.f, 0.f, 0.f};
            } else {
                const float* r = mem + (size_t)s * 512;
                *(f32x4*)&ls[pp][lane * 4]       = *(const f32x4*)&r[lane * 4];
                *(f32x4*)&ls[pp][lane * 4 + 256] = *(const f32x4*)&r[lane * 4 + 256];
            }
        }
        __syncthreads();
        const int cl = lane >> 3;            // 0..7: channel within pass
        const int p4 = (lane & 7) * 4;       // 0,4,..28: pixel quad
        #pragma unroll
        for (int cp = 0; cp < 8; ++cp) {
            const int c = w * 64 + cp * 8 + cl;
            f32x4 v;
            v.x = ls[p4 + 0][c];
            v.y = ls[p4 + 1][c];
            v.z = ls[p4 + 2][c];
            v.w = ls[p4 + 3][c];
            *(f32x4*)&out[((size_t)b * 512 + c) * 4096 + n0 + half * 32 + p4] = v;
        }
        __syncthreads();
    }
}

extern "C" void kernel_launch(void* const* d_in, const int* in_sizes, int n_in,
                              void* d_out, int out_size, void* d_ws, size_t ws_size,
                              hipStream_t stream) {
    const float* x   = (const float*)d_in[0];   // [32,512,64,64]
    const float* mem = (const float*)d_in[1];   // [1024,512]
    short* memnF = (short*)d_ws;                // 1 MiB fragmented bf16
    float* out   = (float*)d_out;

    norm_mem_kernel<<<dim3(1024), dim3(256), 0, stream>>>(mem, memnF);
    simmax_kernel<<<dim3(64, 32), dim3(512), 0, stream>>>(x, memnF, mem, out);
}